// Round 1
// baseline (686.980 us; speedup 1.0000x reference)
//
#include <hip/hip_runtime.h>
#include <math.h>

#define HH 512
#define WW 512
#define W4 (WW/4)
#define NPIX (HH*WW)

__device__ __forceinline__ float fmin3f(float a, float b, float c){ return fminf(fminf(a,b),c); }
__device__ __forceinline__ float fmax3f(float a, float b, float c){ return fmaxf(fmaxf(a,b),c); }

// ---------------- erode: dst = min over valid {C, U, D, L, R} ----------------
__global__ void erode_k(const float* __restrict__ src, float* __restrict__ dst, int total4)
{
    int t = blockIdx.x * blockDim.x + threadIdx.x;
    if (t >= total4) return;
    int xq   = t % W4;
    int rest = t / W4;
    int y    = rest % HH;
    int im   = rest / HH;

    const float* base = src + (size_t)im * NPIX + (size_t)y * WW;
    const float  INF  = INFINITY;

    float4 c = *(const float4*)(base + xq*4);
    float4 up, dn;
    if (y > 0)     up = *(const float4*)(base - WW + xq*4); else up = make_float4(INF,INF,INF,INF);
    if (y < HH-1)  dn = *(const float4*)(base + WW + xq*4); else dn = make_float4(INF,INF,INF,INF);
    float l = (xq > 0)     ? base[xq*4 - 1] : INF;
    float r = (xq < W4-1)  ? base[xq*4 + 4] : INF;

    float4 o;
    o.x = fminf(fminf(up.x, dn.x), fmin3f(l,   c.x, c.y));
    o.y = fminf(fminf(up.y, dn.y), fmin3f(c.x, c.y, c.z));
    o.z = fminf(fminf(up.z, dn.z), fmin3f(c.y, c.z, c.w));
    o.w = fminf(fminf(up.w, dn.w), fmin3f(c.z, c.w, r));

    *(float4*)(dst + (size_t)im * NPIX + (size_t)y * WW + xq*4) = o;
}

// ---------------- 3x3 dilate of e at (im, y, xq*4..xq*4+3) ----------------
__device__ __forceinline__ float4 dilate4(const float* __restrict__ e, int im, int y, int xq)
{
    const float NEG = -INFINITY;
    const float* base = e + (size_t)im * NPIX + (size_t)y * WW;
    float4 acc = make_float4(NEG, NEG, NEG, NEG);
#pragma unroll
    for (int dy = -1; dy <= 1; ++dy) {
        int yy = y + dy;
        if (yy < 0 || yy >= HH) continue;
        const float* row = base + dy * WW;
        float4 c = *(const float4*)(row + xq*4);
        float l = (xq > 0)    ? row[xq*4 - 1] : NEG;
        float r = (xq < W4-1) ? row[xq*4 + 4] : NEG;
        acc.x = fmaxf(acc.x, fmax3f(l,   c.x, c.y));
        acc.y = fmaxf(acc.y, fmax3f(c.x, c.y, c.z));
        acc.z = fmaxf(acc.z, fmax3f(c.y, c.z, c.w));
        acc.w = fmaxf(acc.w, fmax3f(c.z, c.w, r));
    }
    return acc;
}

// ---------------- skel = relu(img - D(e1)) ----------------
__global__ void open_skel_init_k(const float* __restrict__ e1, const float* __restrict__ img,
                                 float* __restrict__ skel, int total4)
{
    int t = blockIdx.x * blockDim.x + threadIdx.x;
    if (t >= total4) return;
    int xq   = t % W4;
    int rest = t / W4;
    int y    = rest % HH;
    int im   = rest / HH;

    float4 d  = dilate4(e1, im, y, xq);
    float4 iv = *(const float4*)(img + (size_t)im * NPIX + (size_t)y * WW + xq*4);
    float4 s;
    s.x = fmaxf(iv.x - d.x, 0.f);
    s.y = fmaxf(iv.y - d.y, 0.f);
    s.z = fmaxf(iv.z - d.z, 0.f);
    s.w = fmaxf(iv.w - d.w, 0.f);
    *(float4*)(skel + (size_t)im * NPIX + (size_t)y * WW + xq*4) = s;
}

// ---------------- delta = relu(eprev - D(ecur)); skel += relu(delta - skel*delta) ----------------
__global__ void open_skel_update_k(const float* __restrict__ ecur, const float* __restrict__ eprev,
                                   float* __restrict__ skel, int total4)
{
    int t = blockIdx.x * blockDim.x + threadIdx.x;
    if (t >= total4) return;
    int xq   = t % W4;
    int rest = t / W4;
    int y    = rest % HH;
    int im   = rest / HH;
    size_t off = (size_t)im * NPIX + (size_t)y * WW + xq*4;

    float4 d  = dilate4(ecur, im, y, xq);
    float4 ep = *(const float4*)(eprev + off);
    float4 s  = *(const float4*)(skel + off);

    float dx = fmaxf(ep.x - d.x, 0.f);
    float dy_ = fmaxf(ep.y - d.y, 0.f);
    float dz = fmaxf(ep.z - d.z, 0.f);
    float dw = fmaxf(ep.w - d.w, 0.f);
    s.x += fmaxf(dx  - s.x * dx , 0.f);
    s.y += fmaxf(dy_ - s.y * dy_, 0.f);
    s.z += fmaxf(dz  - s.z * dz , 0.f);
    s.w += fmaxf(dw  - s.w * dw , 0.f);
    *(float4*)(skel + off) = s;
}

// ---------------- last update fused with reduction: sums2[0]+=sum(skel*other), sums2[1]+=sum(skel) ----------------
__global__ void open_skel_final_k(const float* __restrict__ e4, const float* __restrict__ e3,
                                  const float* __restrict__ skel, const float* __restrict__ other,
                                  double* __restrict__ sums2, int total4)
{
    int t = blockIdx.x * blockDim.x + threadIdx.x;
    float sa = 0.f, sb = 0.f;
    if (t < total4) {
        int xq   = t % W4;
        int rest = t / W4;
        int y    = rest % HH;
        int im   = rest / HH;
        size_t off = (size_t)im * NPIX + (size_t)y * WW + xq*4;

        float4 d  = dilate4(e4, im, y, xq);
        float4 ep = *(const float4*)(e3 + off);
        float4 s  = *(const float4*)(skel + off);
        float4 o  = *(const float4*)(other + off);

        float dx = fmaxf(ep.x - d.x, 0.f);
        float dy_ = fmaxf(ep.y - d.y, 0.f);
        float dz = fmaxf(ep.z - d.z, 0.f);
        float dw = fmaxf(ep.w - d.w, 0.f);
        float nx = s.x + fmaxf(dx  - s.x * dx , 0.f);
        float ny = s.y + fmaxf(dy_ - s.y * dy_, 0.f);
        float nz = s.z + fmaxf(dz  - s.z * dz , 0.f);
        float nw = s.w + fmaxf(dw  - s.w * dw , 0.f);

        sa = nx + ny + nz + nw;
        sb = nx * o.x + ny * o.y + nz * o.z + nw * o.w;
    }
    // wave (64) reduce
#pragma unroll
    for (int offm = 32; offm > 0; offm >>= 1) {
        sa += __shfl_down(sa, offm);
        sb += __shfl_down(sb, offm);
    }
    __shared__ float lsa[4], lsb[4];
    int wid  = threadIdx.x >> 6;
    int lane = threadIdx.x & 63;
    if (lane == 0) { lsa[wid] = sa; lsb[wid] = sb; }
    __syncthreads();
    if (threadIdx.x == 0) {
        float ta = lsa[0] + lsa[1] + lsa[2] + lsa[3];
        float tb = lsb[0] + lsb[1] + lsb[2] + lsb[3];
        atomicAdd(sums2 + 1, (double)ta);   // sum(skel)
        atomicAdd(sums2 + 0, (double)tb);   // sum(skel * other)
    }
}

__global__ void finalize_k(const double* __restrict__ sums, float* __restrict__ out)
{
    double tprec = (sums[0] + 1.0) / (sums[1] + 1.0);
    double tsens = (sums[2] + 1.0) / (sums[3] + 1.0);
    double cl = 1.0 - 2.0 * (tprec * tsens) / (tprec + tsens);
    out[0] = (float)cl;
}

extern "C" void kernel_launch(void* const* d_in, const int* in_sizes, int n_in,
                              void* d_out, int out_size, void* d_ws, size_t ws_size,
                              hipStream_t stream)
{
    const float* y_pred = (const float*)d_in[0];
    const float* y_true = (const float*)d_in[1];
    float* out = (float*)d_out;

    int B = in_sizes[0] / NPIX;   // 32 images, each 512x512

    double* sums = (double*)d_ws;
    char* bufbase = (char*)d_ws + 64;
    size_t avail = (ws_size > 64) ? (ws_size - 64) : 0;
    int chunk = (int)(avail / (3ull * NPIX * sizeof(float)));
    if (chunk > B) chunk = B;
    if (chunk < 1) chunk = 1;

    size_t bufElems = (size_t)chunk * NPIX;
    float* bufA = (float*)bufbase;
    float* bufB = bufA + bufElems;
    float* skel = bufB + bufElems;

    hipMemsetAsync(sums, 0, 4 * sizeof(double), stream);

    for (int chain = 0; chain < 2; ++chain) {
        const float* img   = chain ? y_true : y_pred;
        const float* other = chain ? y_pred : y_true;
        double* s2 = sums + 2 * chain;
        for (int i0 = 0; i0 < B; i0 += chunk) {
            int n = (chunk < B - i0) ? chunk : (B - i0);
            const float* ip = img   + (size_t)i0 * NPIX;
            const float* op = other + (size_t)i0 * NPIX;
            int total4 = n * (NPIX / 4);
            int blocks = (total4 + 255) / 256;

            erode_k          <<<blocks, 256, 0, stream>>>(ip,   bufA, total4);          // e1
            open_skel_init_k <<<blocks, 256, 0, stream>>>(bufA, ip,   skel, total4);    // skel = relu(img - D(e1))
            erode_k          <<<blocks, 256, 0, stream>>>(bufA, bufB, total4);          // e2
            open_skel_update_k<<<blocks,256, 0, stream>>>(bufB, bufA, skel, total4);    // iter 1
            erode_k          <<<blocks, 256, 0, stream>>>(bufB, bufA, total4);          // e3
            open_skel_update_k<<<blocks,256, 0, stream>>>(bufA, bufB, skel, total4);    // iter 2
            erode_k          <<<blocks, 256, 0, stream>>>(bufA, bufB, total4);          // e4
            open_skel_final_k<<<blocks, 256, 0, stream>>>(bufB, bufA, skel, op, s2, total4); // iter 3 + reduce
        }
    }
    finalize_k<<<1, 1, 0, stream>>>(sums, out);
}

// Round 2
// 93.570 us; speedup vs baseline: 7.3419x; 7.3419x over previous
//
#include <hip/hip_runtime.h>
#include <math.h>

#define HH 512
#define WW 512
#define NPIX (HH*WW)

#define TS   64          // output tile
#define BR   74          // buffer rows: 5 + 64 + 5
#define BC   80          // buffer cols: 8 + 64 + 5 (+3 pad, float4-aligned)
#define BC4  (BC/4)
#define ROFF 5           // center row offset in buffer
#define COFF 8           // center col offset in buffer (4-aligned)

// One block = one 64x64 tile of one image of one chain. Computes the entire
// soft_skel chain (e1..e4, 4 open/skel updates) in LDS, skel in registers,
// emits a single float2 partial (sum(skel*other), sum(skel)).
__global__ __launch_bounds__(256, 3)
void cldice_fused_k(const float* __restrict__ y_pred,
                    const float* __restrict__ y_true,
                    float2* __restrict__ partials)
{
    __shared__ float buf[2][BR][BC];
    __shared__ float redA[4], redB[4];

    const int tid   = threadIdx.x;
    const int chain = blockIdx.z;
    const int im    = blockIdx.y;
    const int tileY = blockIdx.x >> 3;
    const int tileX = blockIdx.x & 7;
    const int y0 = tileY * TS;
    const int x0 = tileX * TS;

    const float* __restrict__ imgp = (chain ? y_true : y_pred) + (size_t)im * NPIX;
    const float* __restrict__ othp = (chain ? y_pred : y_true) + (size_t)im * NPIX;

    // ---- load tile + halo, replicate-clamped at image borders ----
    for (int i = tid; i < BR * BC4; i += 256) {
        int r  = i / BC4;
        int c0 = (i - r * BC4) * 4;
        int gy = y0 - ROFF + r;
        gy = min(max(gy, 0), HH - 1);
        int gx = x0 - COFF + c0;
        const float* rowp = imgp + (size_t)gy * WW;
        float4 v;
        if ((unsigned)gx <= (unsigned)(WW - 4)) {
            v = *(const float4*)(rowp + gx);
        } else {
            int g0 = min(max(gx + 0, 0), WW - 1);
            int g1 = min(max(gx + 1, 0), WW - 1);
            int g2 = min(max(gx + 2, 0), WW - 1);
            int g3 = min(max(gx + 3, 0), WW - 1);
            v.x = rowp[g0]; v.y = rowp[g1]; v.z = rowp[g2]; v.w = rowp[g3];
        }
        *(float4*)&buf[0][r][c0] = v;
    }
    __syncthreads();

    const int ty = tid >> 4;           // 16x16 threads over the 64x64 center
    const int tx = tid & 15;
    const int Rr = ROFF + ty * 4;      // this thread's 4 center rows
    const int Cc = COFF + tx * 4;      // this thread's aligned 4-col group

    // image-boundary clamps for the dilate (max must exclude out-of-image)
    const int  rLoD  = (y0 == 0)       ? ROFF            : 0;
    const int  rHiD  = (y0 + TS == HH) ? (ROFF + TS - 1) : (BR - 1);
    const bool leftE  = (x0 == 0)       && (tx == 0);
    const bool rightE = (x0 + TS == WW) && (tx == 15);

    float4 skel[4];
    #pragma unroll
    for (int i = 0; i < 4; ++i) skel[i] = make_float4(0.f, 0.f, 0.f, 0.f);

    int cur = 0;
    #pragma unroll
    for (int stage = 0; stage < 4; ++stage) {
        const float (*S)[BC]   = buf[cur];        // e_{k-1} (stage 0: img)
        float       (*Dst)[BC] = buf[cur ^ 1];    // e_k

        // erode full buffer (buffer-edge clamped reads; over-estimates stay
        // outside the needed frontier; image-edge replicate is exact for min)
        for (int i = tid; i < BR * BC4; i += 256) {
            int r  = i / BC4;
            int c0 = (i - r * BC4) * 4;
            int ru = (r == 0)      ? 0        : r - 1;
            int rd = (r == BR - 1) ? (BR - 1) : r + 1;
            float4 c  = *(const float4*)&S[r][c0];
            float4 up = *(const float4*)&S[ru][c0];
            float4 dn = *(const float4*)&S[rd][c0];
            float  L  = S[r][(c0 == 0)      ? 0        : c0 - 1];
            float  R  = S[r][(c0 == BC - 4) ? (BC - 1) : c0 + 4];
            float4 o;
            o.x = fminf(fminf(fminf(L,   c.x), c.y), fminf(up.x, dn.x));
            o.y = fminf(fminf(fminf(c.x, c.y), c.z), fminf(up.y, dn.y));
            o.z = fminf(fminf(fminf(c.y, c.z), c.w), fminf(up.z, dn.z));
            o.w = fminf(fminf(fminf(c.z, c.w), R),   fminf(up.w, dn.w));
            *(float4*)&Dst[r][c0] = o;
        }
        __syncthreads();

        // dilate(e_k) at center + skel update (skel=0 makes init == update)
        const float (*Ek)[BC] = buf[cur ^ 1];
        const float (*Pv)[BC] = buf[cur];

        float4 hm[6];
        #pragma unroll
        for (int i = 0; i < 6; ++i) {
            int q = min(max(Rr - 1 + i, rLoD), rHiD);   // row-replicate at image edge
            float4 c = *(const float4*)&Ek[q][Cc];
            float  L = Ek[q][Cc - 1];
            float  R = Ek[q][Cc + 4];
            float4 h;
            h.x = fmaxf(fmaxf(L,   c.x), c.y);
            h.y = fmaxf(fmaxf(c.x, c.y), c.z);
            h.z = fmaxf(fmaxf(c.y, c.z), c.w);
            h.w = fmaxf(fmaxf(c.z, c.w), R);
            if (leftE)  h.x = fmaxf(c.x, c.y);          // exclude out-of-image left
            if (rightE) h.w = fmaxf(c.z, c.w);          // exclude out-of-image right
            hm[i] = h;
        }
        #pragma unroll
        for (int i = 0; i < 4; ++i) {
            float4 d;
            d.x = fmaxf(fmaxf(hm[i].x, hm[i+1].x), hm[i+2].x);
            d.y = fmaxf(fmaxf(hm[i].y, hm[i+1].y), hm[i+2].y);
            d.z = fmaxf(fmaxf(hm[i].z, hm[i+1].z), hm[i+2].z);
            d.w = fmaxf(fmaxf(hm[i].w, hm[i+1].w), hm[i+2].w);
            float4 p = *(const float4*)&Pv[Rr + i][Cc];
            float4 dl;
            dl.x = fmaxf(p.x - d.x, 0.f);
            dl.y = fmaxf(p.y - d.y, 0.f);
            dl.z = fmaxf(p.z - d.z, 0.f);
            dl.w = fmaxf(p.w - d.w, 0.f);
            skel[i].x += fmaxf(dl.x - skel[i].x * dl.x, 0.f);
            skel[i].y += fmaxf(dl.y - skel[i].y * dl.y, 0.f);
            skel[i].z += fmaxf(dl.z - skel[i].z * dl.z, 0.f);
            skel[i].w += fmaxf(dl.w - skel[i].w * dl.w, 0.f);
        }
        __syncthreads();
        cur ^= 1;
    }

    // ---- per-tile reduction: one float2 partial per block, no atomics ----
    float sa = 0.f, sb = 0.f;
    #pragma unroll
    for (int i = 0; i < 4; ++i) {
        int gy = y0 + ty * 4 + i;
        int gx = x0 + tx * 4;
        float4 o = *(const float4*)(othp + (size_t)gy * WW + gx);
        sa += (skel[i].x + skel[i].y) + (skel[i].z + skel[i].w);
        sb += skel[i].x * o.x + skel[i].y * o.y + skel[i].z * o.z + skel[i].w * o.w;
    }
    #pragma unroll
    for (int off = 32; off; off >>= 1) {
        sa += __shfl_down(sa, off);
        sb += __shfl_down(sb, off);
    }
    int wid = tid >> 6, lane = tid & 63;
    if (lane == 0) { redA[wid] = sa; redB[wid] = sb; }
    __syncthreads();
    if (tid == 0) {
        float ta = (redA[0] + redA[1]) + (redA[2] + redA[3]);
        float tb = (redB[0] + redB[1]) + (redB[2] + redB[3]);
        int ntile = gridDim.x * gridDim.y;
        int pidx  = chain * ntile + im * gridDim.x + blockIdx.x;
        partials[pidx] = make_float2(tb, ta);   // (.x = sum skel*other, .y = sum skel)
    }
}

__global__ void cldice_final_k(const float2* __restrict__ partials, int ntile,
                               float* __restrict__ out)
{
    double s0 = 0, s1 = 0, s2 = 0, s3 = 0;
    for (int i = threadIdx.x; i < ntile; i += 256) {
        float2 p = partials[i];            // chain 0: skel_pred
        s0 += p.x; s1 += p.y;
        float2 q = partials[ntile + i];    // chain 1: skel_true
        s2 += q.x; s3 += q.y;
    }
    #pragma unroll
    for (int off = 32; off; off >>= 1) {
        s0 += __shfl_down(s0, off);
        s1 += __shfl_down(s1, off);
        s2 += __shfl_down(s2, off);
        s3 += __shfl_down(s3, off);
    }
    __shared__ double sm[4][4];
    int wid = threadIdx.x >> 6, lane = threadIdx.x & 63;
    if (lane == 0) { sm[0][wid] = s0; sm[1][wid] = s1; sm[2][wid] = s2; sm[3][wid] = s3; }
    __syncthreads();
    if (threadIdx.x == 0) {
        double S0 = sm[0][0] + sm[0][1] + sm[0][2] + sm[0][3];
        double S1 = sm[1][0] + sm[1][1] + sm[1][2] + sm[1][3];
        double S2 = sm[2][0] + sm[2][1] + sm[2][2] + sm[2][3];
        double S3 = sm[3][0] + sm[3][1] + sm[3][2] + sm[3][3];
        double tprec = (S0 + 1.0) / (S1 + 1.0);
        double tsens = (S2 + 1.0) / (S3 + 1.0);
        out[0] = (float)(1.0 - 2.0 * (tprec * tsens) / (tprec + tsens));
    }
}

extern "C" void kernel_launch(void* const* d_in, const int* in_sizes, int n_in,
                              void* d_out, int out_size, void* d_ws, size_t ws_size,
                              hipStream_t stream)
{
    const float* y_pred = (const float*)d_in[0];
    const float* y_true = (const float*)d_in[1];
    int B = in_sizes[0] / NPIX;            // 32 images

    float2* partials = (float2*)d_ws;      // 2 * B * 64 float2 = 32 KB for B=32
    dim3 grid(64, B, 2);                   // 8x8 tiles, B images, 2 chains
    cldice_fused_k<<<grid, 256, 0, stream>>>(y_pred, y_true, partials);

    int ntile = 64 * B;
    cldice_final_k<<<1, 256, 0, stream>>>(partials, ntile, (float*)d_out);
}